// Round 5
// baseline (8583.096 us; speedup 1.0000x reference)
//
#include <hip/hip_runtime.h>

typedef unsigned short u16;
typedef _Float16 f16;
typedef __attribute__((ext_vector_type(8))) _Float16 f16x8;
typedef __attribute__((ext_vector_type(8))) unsigned short u16x8;
typedef __attribute__((ext_vector_type(4))) float f32x4;

#define NWG 32

// returns hi f16 bits in [15:0], lo f16 bits (residual * 2048) in [31:16]
__device__ __forceinline__ unsigned split2(float v) {
  f16 h = (f16)v;
  f16 l2 = (f16)((v - (float)h) * 2048.0f);
  return (unsigned)__builtin_bit_cast(u16, h) | ((unsigned)__builtin_bit_cast(u16, l2) << 16);
}

// ---- zero scratch control state (istats + barrier counters) ----
__global__ void k_zero(unsigned long long* __restrict__ ist, unsigned* __restrict__ bar) {
  int tid = threadIdx.x;
  if (tid < 256) ist[tid] = 0ull;
  if (tid < 16) bar[tid] = 0u;
}

// ---- transpose+split wx [2][512][2048] fp32 -> wxT hi/lo [2][2048][512] f16 ----
__global__ void k_wsplit(const float* __restrict__ wx, u16* __restrict__ th, u16* __restrict__ tl) {
  __shared__ float tile[32][33];
  int l = blockIdx.z;
  int n0 = blockIdx.x * 32, k0 = blockIdx.y * 32;
  int tx = threadIdx.x, ty = threadIdx.y;
  const float* src = wx + (size_t)l * 512 * 2048;
#pragma unroll
  for (int i = 0; i < 4; ++i)
    tile[ty + i * 8][tx] = src[(size_t)(k0 + ty + i * 8) * 2048 + n0 + tx];
  __syncthreads();
  u16* dh = th + (size_t)l * 2048 * 512;
  u16* dl = tl + (size_t)l * 2048 * 512;
#pragma unroll
  for (int i = 0; i < 4; ++i) {
    unsigned s = split2(tile[tx][ty + i * 8]);
    dh[(size_t)(n0 + ty + i * 8) * 512 + k0 + tx] = (u16)s;
    dl[(size_t)(n0 + ty + i * 8) * 512 + k0 + tx] = (u16)(s >> 16);
  }
}

// ---- pack wh_lo into MFMA-B fragment order: wlo[l][g(32)][q(4)][kc(16)][lane(64)][8] ----
// exactly 2*32*4*16*64 = 262144 threads; g<32 so gcol<2048 (no OOB).
__global__ void k_wlo(const float* __restrict__ wh, u16* __restrict__ wlo) {
  int idx = blockIdx.x * blockDim.x + threadIdx.x; // 262144 total
  int l = idx >> 17;
  int r = idx & 131071;
  int lane = r & 63;
  int fg = r >> 6; // [0,2048)
  int kc = fg & 15, q = (fg >> 4) & 3, g = fg >> 6; // g in [0,32)
  int gcol = g * 16 + (lane & 15) + q * 512;
  int kb = kc * 32 + ((lane >> 4) << 3);
  const float* W = wh + (size_t)l * 512 * 2048;
  u16x8 o;
#pragma unroll
  for (int j = 0; j < 8; ++j)
    o[j] = (u16)(split2(W[(size_t)(kb + j) * 2048 + gcol]) >> 16);
  *(u16x8*)(wlo + (size_t)idx * 8) = o;
}

// ---- split-fp16 GEMM: A fp32 [8192,K] (split on the fly), Bt hi/lo [N,K] f16 -> C fp32 ----
__global__ void __launch_bounds__(256, 1) k_gemm3(const float* __restrict__ A,
                                                  const u16* __restrict__ Bh, const u16* __restrict__ Bl,
                                                  float* __restrict__ C, int N, int K) {
  __shared__ u16 sA[2][128 * 64];
  __shared__ u16 sB[2][128 * 64];
  const int tid = threadIdx.x, l = tid & 63, w = tid >> 6;
  const int bx = blockIdx.x, by = blockIdx.y;
  const int wr = (w >> 1) * 64, wc = (w & 1) * 64;
  f32x4 acc0[4][4] = {}, acc1[4][4] = {};
  for (int k0 = 0; k0 < K; k0 += 64) {
#pragma unroll
    for (int s = 0; s < 4; ++s) {
      int cn = s * 256 + tid;
      int row = cn >> 3;
      int f0 = (cn & 7) * 8;             // float offset within 64-wide K slice
      int kb = f0 * 2;                   // byte offset within 128B LDS row
      int sw = row * 128 + (kb ^ ((row & 7) << 4));
      const float* ap = A + ((size_t)(by * 128 + row) * K + k0 + f0);
      float4 a0 = *(const float4*)ap, a1 = *(const float4*)(ap + 4);
      float av[8] = {a0.x, a0.y, a0.z, a0.w, a1.x, a1.y, a1.z, a1.w};
      u16x8 ah_, al_;
#pragma unroll
      for (int j = 0; j < 8; ++j) {
        unsigned sp = split2(av[j]);
        ah_[j] = (u16)sp;
        al_[j] = (u16)(sp >> 16);
      }
      *(u16x8*)((char*)sA[0] + sw) = ah_;
      *(u16x8*)((char*)sA[1] + sw) = al_;
      size_t gb = (((size_t)(bx * 128 + row) * K + k0) << 1) + kb;
      *(u16x8*)((char*)sB[0] + sw) = *(const u16x8*)((const char*)Bh + gb);
      *(u16x8*)((char*)sB[1] + sw) = *(const u16x8*)((const char*)Bl + gb);
    }
    __syncthreads();
#pragma unroll
    for (int kc = 0; kc < 2; ++kc) {
      int kb = kc * 64 + (l >> 4) * 16;
      f16x8 ah[4], al[4], bh[4], bl[4];
#pragma unroll
      for (int mt = 0; mt < 4; ++mt) {
        int row = wr + mt * 16 + (l & 15);
        int off = row * 128 + (kb ^ ((row & 7) << 4));
        ah[mt] = *(const f16x8*)((const char*)sA[0] + off);
        al[mt] = *(const f16x8*)((const char*)sA[1] + off);
      }
#pragma unroll
      for (int nt = 0; nt < 4; ++nt) {
        int col = wc + nt * 16 + (l & 15);
        int off = col * 128 + (kb ^ ((col & 7) << 4));
        bh[nt] = *(const f16x8*)((const char*)sB[0] + off);
        bl[nt] = *(const f16x8*)((const char*)sB[1] + off);
      }
#pragma unroll
      for (int mt = 0; mt < 4; ++mt)
#pragma unroll
        for (int nt = 0; nt < 4; ++nt) {
          acc0[mt][nt] = __builtin_amdgcn_mfma_f32_16x16x32_f16(ah[mt], bh[nt], acc0[mt][nt], 0, 0, 0);
          acc1[mt][nt] = __builtin_amdgcn_mfma_f32_16x16x32_f16(ah[mt], bl[nt], acc1[mt][nt], 0, 0, 0);
          acc1[mt][nt] = __builtin_amdgcn_mfma_f32_16x16x32_f16(al[mt], bh[nt], acc1[mt][nt], 0, 0, 0);
        }
    }
    __syncthreads();
  }
#pragma unroll
  for (int mt = 0; mt < 4; ++mt)
#pragma unroll
    for (int nt = 0; nt < 4; ++nt)
#pragma unroll
      for (int j = 0; j < 4; ++j) {
        int row = by * 128 + wr + mt * 16 + ((l >> 4) << 2) + j;
        int col = bx * 128 + wc + nt * 16 + (l & 15);
        C[(size_t)row * N + col] = acc0[mt][nt][j] + acc1[mt][nt][j] * (1.0f / 2048.0f);
      }
}

// ---- in-place fp32 row LayerNorm [rows][2048]: y = (x-mu)*rstd*g + b + bias ----
__global__ void __launch_bounds__(256) k_ln2(float* __restrict__ X, const float* __restrict__ g,
                                             const float* __restrict__ b, const float* __restrict__ bias) {
  const int row = blockIdx.x, tid = threadIdx.x;
  float* rp = X + (size_t)row * 2048 + tid * 8;
  float4 v0 = *(const float4*)rp, v1 = *(const float4*)(rp + 4);
  float x[8] = {v0.x, v0.y, v0.z, v0.w, v1.x, v1.y, v1.z, v1.w};
  float s1 = 0.f, s2 = 0.f;
#pragma unroll
  for (int j = 0; j < 8; ++j) { s1 += x[j]; s2 += x[j] * x[j]; }
#pragma unroll
  for (int m = 1; m <= 32; m <<= 1) { s1 += __shfl_xor(s1, m, 64); s2 += __shfl_xor(s2, m, 64); }
  __shared__ float a1[4], a2[4];
  if ((tid & 63) == 0) { a1[tid >> 6] = s1; a2[tid >> 6] = s2; }
  __syncthreads();
  s1 = a1[0] + a1[1] + a1[2] + a1[3];
  s2 = a2[0] + a2[1] + a2[2] + a2[3];
  float mu = s1 * (1.f / 2048.f);
  float var = s2 * (1.f / 2048.f) - mu * mu;
  float rstd = 1.0f / sqrtf(var + 1e-5f);
#pragma unroll
  for (int j = 0; j < 8; ++j) {
    int c = tid * 8 + j;
    x[j] = (x[j] - mu) * rstd * g[c] + b[c] + bias[c];
  }
  *(float4*)rp = {x[0], x[1], x[2], x[3]};
  *(float4*)(rp + 4) = {x[4], x[5], x[6], x[7]};
}

// ---- persistent LSTM scan (one 128-step chunk), split-fp16 recurrent matmul ----
// 32 WGs x 256 threads. WG g owns hidden cols [16g,16g+16); wave w owns batch rows [16w,16w+16).
__global__ void __launch_bounds__(256, 1) k_scan3(
    const float* __restrict__ wh, const u16* __restrict__ wlo,
    const float* __restrict__ gh, const float* __restrict__ bh,
    const float* __restrict__ xn, const float* __restrict__ h0l, const float* __restrict__ c0l,
    u16* __restrict__ hpubh, u16* __restrict__ hpubl, float* __restrict__ cspill,
    unsigned long long* __restrict__ istats, unsigned* __restrict__ barcnt,
    float* __restrict__ ys, float* __restrict__ hn, float* __restrict__ cn,
    int t0, int first) {
  __shared__ u16 pk[32768]; // 64KB: wh_hi fragments [q][kc][lane][8]
  const int tid = threadIdx.x;
  const int l = tid & 63, w = tid >> 6;
  const int g = blockIdx.x;
  const int lq = l >> 4, ll = l & 15;
  const int hcol = g * 16 + ll;

  // pack wh_hi slice into LDS in B-fragment order
  for (int c = tid; c < 4096; c += 256) {
    int lane = c & 63, kc = (c >> 6) & 15, q = c >> 10;
    int gcol = g * 16 + (lane & 15) + q * 512;
    int kb = kc * 32 + ((lane >> 4) << 3);
    u16x8 t8;
#pragma unroll
    for (int j = 0; j < 8; ++j)
      t8[j] = __builtin_bit_cast(u16, (f16)wh[(size_t)(kb + j) * 2048 + gcol]);
    *(u16x8*)(pk + (size_t)c * 8) = t8;
  }
  const u16* wloG = wlo + (size_t)g * 32768;
  float gam[4], bet[4];
#pragma unroll
  for (int q = 0; q < 4; ++q) { int gc = hcol + q * 512; gam[q] = gh[gc]; bet[q] = bh[gc]; }
  float cr[4];
#pragma unroll
  for (int j = 0; j < 4; ++j) {
    int r = w * 16 + lq * 4 + j;
    cr[j] = first ? c0l[r * 512 + hcol] : cspill[r * 512 + hcol];
  }
  if (first) { // init hpub rows 2g, 2g+1 from h0
    for (int u = tid; u < 1024; u += 256) {
      int row = 2 * g + (u >> 9), col = u & 511;
      unsigned s = split2(h0l[row * 512 + col]);
      hpubh[row * 512 + col] = (u16)s;
      hpubl[row * 512 + col] = (u16)(s >> 16);
    }
  }
  unsigned epoch = 0;
#define GRID_BAR()                                                                           \
  do {                                                                                       \
    epoch++;                                                                                 \
    __syncthreads();                                                                         \
    if (tid == 0) {                                                                          \
      __threadfence();                                                                       \
      __hip_atomic_fetch_add(barcnt, 1u, __ATOMIC_RELAXED, __HIP_MEMORY_SCOPE_AGENT);        \
      while (__hip_atomic_load(barcnt, __ATOMIC_RELAXED, __HIP_MEMORY_SCOPE_AGENT) <         \
             epoch * (unsigned)NWG) {}                                                       \
      __threadfence();                                                                       \
    }                                                                                        \
    __syncthreads();                                                                         \
  } while (0)

  GRID_BAR();

  for (int t = 0; t < 128; ++t) {
    const int p = (t0 + t) & 1;
    float xp[16];
    const float* xrow = xn + (size_t)t * 64 * 2048;
#pragma unroll
    for (int q = 0; q < 4; ++q)
#pragma unroll
      for (int j = 0; j < 4; ++j)
        xp[q * 4 + j] = xrow[(size_t)(w * 16 + lq * 4 + j) * 2048 + hcol + q * 512];

    f32x4 acc0[4] = {}, acc1[4] = {};
#pragma unroll
    for (int kc = 0; kc < 16; ++kc) {
      size_t aoff = (size_t)(w * 16 + ll) * 512 + kc * 32 + lq * 8;
      f16x8 ah = *(const f16x8*)(hpubh + aoff);
      f16x8 al = *(const f16x8*)(hpubl + aoff);
#pragma unroll
      for (int q = 0; q < 4; ++q) {
        f16x8 bhv = *(const f16x8*)(pk + ((size_t)(q * 16 + kc) * 64 + l) * 8);
        f16x8 blv = *(const f16x8*)(wloG + ((size_t)(q * 16 + kc) * 64 + l) * 8);
        acc0[q] = __builtin_amdgcn_mfma_f32_16x16x32_f16(ah, bhv, acc0[q], 0, 0, 0);
        acc1[q] = __builtin_amdgcn_mfma_f32_16x16x32_f16(ah, blv, acc1[q], 0, 0, 0);
        acc1[q] = __builtin_amdgcn_mfma_f32_16x16x32_f16(al, bhv, acc1[q], 0, 0, 0);
      }
    }
    float y[4][4]; // [q][j]
#pragma unroll
    for (int q = 0; q < 4; ++q)
#pragma unroll
      for (int j = 0; j < 4; ++j)
        y[q][j] = acc0[q][j] + acc1[q][j] * (1.0f / 2048.0f);

    // deterministic LN stats: fp32 partial per WG -> fixed-point i64 atomic combine
    float s1[4], s2[4];
#pragma unroll
    for (int j = 0; j < 4; ++j) {
      s1[j] = y[0][j] + y[1][j] + y[2][j] + y[3][j];
      s2[j] = y[0][j] * y[0][j] + y[1][j] * y[1][j] + y[2][j] * y[2][j] + y[3][j] * y[3][j];
    }
#pragma unroll
    for (int m = 1; m <= 8; m <<= 1)
#pragma unroll
      for (int j = 0; j < 4; ++j) {
        s1[j] += __shfl_xor(s1[j], m, 64);
        s2[j] += __shfl_xor(s2[j], m, 64);
      }
    if (ll < 8) {
      int j = ll >> 1;
      int r = w * 16 + lq * 4 + j;
      float v = (ll & 1) ? s2[j] : s1[j];
      long long qv = (long long)((double)v * 4294967296.0);
      atomicAdd(&istats[p * 128 + r * 2 + (ll & 1)], (unsigned long long)qv);
    }
    GRID_BAR(); // stats complete
    if (tid < 4)
      __hip_atomic_store(&istats[(1 - p) * 128 + g * 4 + tid], 0ull, __ATOMIC_RELAXED,
                         __HIP_MEMORY_SCOPE_AGENT);
#pragma unroll
    for (int j = 0; j < 4; ++j) {
      int r = w * 16 + lq * 4 + j;
      long long a1 = (long long)__hip_atomic_load(&istats[p * 128 + r * 2], __ATOMIC_RELAXED,
                                                  __HIP_MEMORY_SCOPE_AGENT);
      long long a2 = (long long)__hip_atomic_load(&istats[p * 128 + r * 2 + 1], __ATOMIC_RELAXED,
                                                  __HIP_MEMORY_SCOPE_AGENT);
      float mu = (float)((double)a1 * (1.0 / (4294967296.0 * 2048.0)));
      float ex2 = (float)((double)a2 * (1.0 / (4294967296.0 * 2048.0)));
      float rstd = 1.0f / sqrtf(ex2 - mu * mu + 1e-5f);
      float gv[4];
#pragma unroll
      for (int q = 0; q < 4; ++q)
        gv[q] = (y[q][j] - mu) * rstd * gam[q] + bet[q] + xp[q * 4 + j];
      float fi = 1.f / (1.f + expf(-gv[0]));
      float ff = 1.f / (1.f + expf(-gv[1]));
      float fo = 1.f / (1.f + expf(-gv[2]));
      float fu = tanhf(gv[3]);
      cr[j] = ff * cr[j] + fi * fu;
      float h = fo * tanhf(cr[j]);
      unsigned s = split2(h);
      size_t ro = (size_t)r * 512 + hcol;
      hpubh[ro] = (u16)s;
      hpubl[ro] = (u16)(s >> 16);
      ys[(size_t)t * 32768 + ro] = h;
      if (t == 127) cspill[ro] = cr[j];
      if (t0 + t == 255) { hn[ro] = h; cn[ro] = cr[j]; }
    }
    GRID_BAR(); // h published
  }
#undef GRID_BAR
}

// ---- workspace layout (bytes), max ~80.0 MB (proven-safe: R0 ran at 88.1 MB) ----
#define XN_OFF  0ull         // 128*64*2048 fp32 = 64MB (xn chunk)
#define WXH_OFF 67108864ull  // 2*2048*512 f16 = 4MB
#define WXL_OFF 71303168ull  // 4MB
#define WLO_OFF 75497472ull  // 2*131072*8 u16 = 4MB
#define HPH_OFF 79691776ull  // 64KB
#define HPL_OFF 79757312ull  // 64KB
#define CSP_OFF 79822848ull  // 64*512 f32 = 128KB
#define IST_OFF 79953920ull  // 256 u64 = 2KB
#define BAR_OFF 79955968ull  // 16 u32

extern "C" void kernel_launch(void* const* d_in, const int* in_sizes, int n_in,
                              void* d_out, int out_size, void* d_ws, size_t ws_size,
                              hipStream_t stream) {
  const float* inputs = (const float*)d_in[0];
  const float* h0 = (const float*)d_in[1];
  const float* c0 = (const float*)d_in[2];
  const float* wx = (const float*)d_in[3];
  const float* wh = (const float*)d_in[4];
  const float* bias = (const float*)d_in[5];
  const float* gx = (const float*)d_in[6];
  const float* bxp = (const float*)d_in[7];
  const float* ghp = (const float*)d_in[8];
  const float* bhp = (const float*)d_in[9];
  float* out = (float*)d_out;
  char* ws = (char*)d_ws;

  float* xn = (float*)(ws + XN_OFF);
  u16* wxh = (u16*)(ws + WXH_OFF);
  u16* wxl = (u16*)(ws + WXL_OFF);
  u16* wlo = (u16*)(ws + WLO_OFF);
  u16* hph = (u16*)(ws + HPH_OFF);
  u16* hpl = (u16*)(ws + HPL_OFF);
  float* csp = (float*)(ws + CSP_OFF);
  unsigned long long* ist = (unsigned long long*)(ws + IST_OFF);
  unsigned* bar = (unsigned*)(ws + BAR_OFF);

  k_zero<<<1, 256, 0, stream>>>(ist, bar);
  k_wsplit<<<dim3(64, 16, 2), dim3(32, 8), 0, stream>>>(wx, wxh, wxl);
  k_wlo<<<1024, 256, 0, stream>>>(wh, wlo);

  for (int l = 0; l < 2; ++l) {
    const float* Abase = (l == 0) ? inputs : out; // layer-1 input = layer-0 ys (fp32 in d_out.x)
    for (int k = 0; k < 2; ++k) {
      k_gemm3<<<dim3(16, 64), 256, 0, stream>>>(Abase + (size_t)k * 8192 * 512,
                                                wxh + (size_t)l * 2048 * 512,
                                                wxl + (size_t)l * 2048 * 512, xn, 2048, 512);
      k_ln2<<<8192, 256, 0, stream>>>(xn, gx + l * 2048, bxp + l * 2048, bias + l * 2048);
      k_scan3<<<NWG, 256, 0, stream>>>(wh + (size_t)l * 1048576, wlo + (size_t)l * 1048576,
                                       ghp + l * 2048, bhp + l * 2048, xn,
                                       h0 + (size_t)l * 32768, c0 + (size_t)l * 32768,
                                       hph, hpl, csp, ist, bar + (l * 2 + k),
                                       out + (size_t)k * 128 * 32768,
                                       out + 8388608 + (size_t)l * 32768,
                                       out + 8388608 + 65536 + (size_t)l * 32768,
                                       k * 128, (k == 0) ? 1 : 0);
    }
  }
}

// Round 6
// 7426.962 us; speedup vs baseline: 1.1557x; 1.1557x over previous
//
#include <hip/hip_runtime.h>

typedef unsigned short u16;
typedef _Float16 f16;
typedef __attribute__((ext_vector_type(8))) _Float16 f16x8;
typedef __attribute__((ext_vector_type(8))) unsigned short u16x8;
typedef __attribute__((ext_vector_type(4))) float f32x4;
typedef __attribute__((ext_vector_type(4))) unsigned u32x4;

#define NWG 32

// returns hi f16 bits in [15:0], lo f16 bits (residual * 2048) in [31:16]
__device__ __forceinline__ unsigned split2(float v) {
  f16 h = (f16)v;
  f16 l2 = (f16)((v - (float)h) * 2048.0f);
  return (unsigned)__builtin_bit_cast(u16, h) | ((unsigned)__builtin_bit_cast(u16, l2) << 16);
}

// ---- zero scratch control state (istats + flag array) ----
__global__ void k_zero(unsigned long long* __restrict__ ist, unsigned* __restrict__ flg) {
  int i = blockIdx.x * blockDim.x + threadIdx.x;
  if (i < 256) ist[i] = 0ull;
  if (i < 8192) flg[i] = 0u;
}

// ---- transpose+split wx [2][512][2048] fp32 -> wxT hi/lo [2][2048][512] f16 ----
__global__ void k_wsplit(const float* __restrict__ wx, u16* __restrict__ th, u16* __restrict__ tl) {
  __shared__ float tile[32][33];
  int l = blockIdx.z;
  int n0 = blockIdx.x * 32, k0 = blockIdx.y * 32;
  int tx = threadIdx.x, ty = threadIdx.y;
  const float* src = wx + (size_t)l * 512 * 2048;
#pragma unroll
  for (int i = 0; i < 4; ++i)
    tile[ty + i * 8][tx] = src[(size_t)(k0 + ty + i * 8) * 2048 + n0 + tx];
  __syncthreads();
  u16* dh = th + (size_t)l * 2048 * 512;
  u16* dl = tl + (size_t)l * 2048 * 512;
#pragma unroll
  for (int i = 0; i < 4; ++i) {
    unsigned s = split2(tile[tx][ty + i * 8]);
    dh[(size_t)(n0 + ty + i * 8) * 512 + k0 + tx] = (u16)s;
    dl[(size_t)(n0 + ty + i * 8) * 512 + k0 + tx] = (u16)(s >> 16);
  }
}

// ---- pack wh_lo into MFMA-B fragment order: wlo[l][g(32)][q(4)][kc(16)][lane(64)][8] ----
__global__ void k_wlo(const float* __restrict__ wh, u16* __restrict__ wlo) {
  int idx = blockIdx.x * blockDim.x + threadIdx.x; // 262144 total
  int l = idx >> 17;
  int r = idx & 131071;
  int lane = r & 63;
  int fg = r >> 6; // [0,2048)
  int kc = fg & 15, q = (fg >> 4) & 3, g = fg >> 6; // g in [0,32)
  int gcol = g * 16 + (lane & 15) + q * 512;
  int kb = kc * 32 + ((lane >> 4) << 3);
  const float* W = wh + (size_t)l * 512 * 2048;
  u16x8 o;
#pragma unroll
  for (int j = 0; j < 8; ++j)
    o[j] = (u16)(split2(W[(size_t)(kb + j) * 2048 + gcol]) >> 16);
  *(u16x8*)(wlo + (size_t)idx * 8) = o;
}

// ---- split-fp16 GEMM: A fp32 [8192,K] (split on the fly), Bt hi/lo [N,K] f16 -> C fp32 ----
__global__ void __launch_bounds__(256, 1) k_gemm3(const float* __restrict__ A,
                                                  const u16* __restrict__ Bh, const u16* __restrict__ Bl,
                                                  float* __restrict__ C, int N, int K) {
  __shared__ u16 sA[2][128 * 64];
  __shared__ u16 sB[2][128 * 64];
  const int tid = threadIdx.x, l = tid & 63, w = tid >> 6;
  const int bx = blockIdx.x, by = blockIdx.y;
  const int wr = (w >> 1) * 64, wc = (w & 1) * 64;
  f32x4 acc0[4][4] = {}, acc1[4][4] = {};
  for (int k0 = 0; k0 < K; k0 += 64) {
#pragma unroll
    for (int s = 0; s < 4; ++s) {
      int cn = s * 256 + tid;
      int row = cn >> 3;
      int f0 = (cn & 7) * 8;
      int kb = f0 * 2;
      int sw = row * 128 + (kb ^ ((row & 7) << 4));
      const float* ap = A + ((size_t)(by * 128 + row) * K + k0 + f0);
      float4 a0 = *(const float4*)ap, a1 = *(const float4*)(ap + 4);
      float av[8] = {a0.x, a0.y, a0.z, a0.w, a1.x, a1.y, a1.z, a1.w};
      u16x8 ah_, al_;
#pragma unroll
      for (int j = 0; j < 8; ++j) {
        unsigned sp = split2(av[j]);
        ah_[j] = (u16)sp;
        al_[j] = (u16)(sp >> 16);
      }
      *(u16x8*)((char*)sA[0] + sw) = ah_;
      *(u16x8*)((char*)sA[1] + sw) = al_;
      size_t gb = (((size_t)(bx * 128 + row) * K + k0) << 1) + kb;
      *(u16x8*)((char*)sB[0] + sw) = *(const u16x8*)((const char*)Bh + gb);
      *(u16x8*)((char*)sB[1] + sw) = *(const u16x8*)((const char*)Bl + gb);
    }
    __syncthreads();
#pragma unroll
    for (int kc = 0; kc < 2; ++kc) {
      int kb = kc * 64 + (l >> 4) * 16;
      f16x8 ah[4], al[4], bh[4], bl[4];
#pragma unroll
      for (int mt = 0; mt < 4; ++mt) {
        int row = wr + mt * 16 + (l & 15);
        int off = row * 128 + (kb ^ ((row & 7) << 4));
        ah[mt] = *(const f16x8*)((const char*)sA[0] + off);
        al[mt] = *(const f16x8*)((const char*)sA[1] + off);
      }
#pragma unroll
      for (int nt = 0; nt < 4; ++nt) {
        int col = wc + nt * 16 + (l & 15);
        int off = col * 128 + (kb ^ ((col & 7) << 4));
        bh[nt] = *(const f16x8*)((const char*)sB[0] + off);
        bl[nt] = *(const f16x8*)((const char*)sB[1] + off);
      }
#pragma unroll
      for (int mt = 0; mt < 4; ++mt)
#pragma unroll
        for (int nt = 0; nt < 4; ++nt) {
          acc0[mt][nt] = __builtin_amdgcn_mfma_f32_16x16x32_f16(ah[mt], bh[nt], acc0[mt][nt], 0, 0, 0);
          acc1[mt][nt] = __builtin_amdgcn_mfma_f32_16x16x32_f16(ah[mt], bl[nt], acc1[mt][nt], 0, 0, 0);
          acc1[mt][nt] = __builtin_amdgcn_mfma_f32_16x16x32_f16(al[mt], bh[nt], acc1[mt][nt], 0, 0, 0);
        }
    }
    __syncthreads();
  }
#pragma unroll
  for (int mt = 0; mt < 4; ++mt)
#pragma unroll
    for (int nt = 0; nt < 4; ++nt)
#pragma unroll
      for (int j = 0; j < 4; ++j) {
        int row = by * 128 + wr + mt * 16 + ((l >> 4) << 2) + j;
        int col = bx * 128 + wc + nt * 16 + (l & 15);
        C[(size_t)row * N + col] = acc0[mt][nt][j] + acc1[mt][nt][j] * (1.0f / 2048.0f);
      }
}

// ---- in-place fp32 row LayerNorm [rows][2048]: y = (x-mu)*rstd*g + b + bias ----
__global__ void __launch_bounds__(256) k_ln2(float* __restrict__ X, const float* __restrict__ g,
                                             const float* __restrict__ b, const float* __restrict__ bias) {
  const int row = blockIdx.x, tid = threadIdx.x;
  float* rp = X + (size_t)row * 2048 + tid * 8;
  float4 v0 = *(const float4*)rp, v1 = *(const float4*)(rp + 4);
  float x[8] = {v0.x, v0.y, v0.z, v0.w, v1.x, v1.y, v1.z, v1.w};
  float s1 = 0.f, s2 = 0.f;
#pragma unroll
  for (int j = 0; j < 8; ++j) { s1 += x[j]; s2 += x[j] * x[j]; }
#pragma unroll
  for (int m = 1; m <= 32; m <<= 1) { s1 += __shfl_xor(s1, m, 64); s2 += __shfl_xor(s2, m, 64); }
  __shared__ float a1[4], a2[4];
  if ((tid & 63) == 0) { a1[tid >> 6] = s1; a2[tid >> 6] = s2; }
  __syncthreads();
  s1 = a1[0] + a1[1] + a1[2] + a1[3];
  s2 = a2[0] + a2[1] + a2[2] + a2[3];
  float mu = s1 * (1.f / 2048.f);
  float var = s2 * (1.f / 2048.f) - mu * mu;
  float rstd = 1.0f / sqrtf(var + 1e-5f);
#pragma unroll
  for (int j = 0; j < 8; ++j) {
    int c = tid * 8 + j;
    x[j] = (x[j] - mu) * rstd * g[c] + b[c] + bias[c];
  }
  *(float4*)rp = {x[0], x[1], x[2], x[3]};
  *(float4*)(rp + 4) = {x[4], x[5], x[6], x[7]};
}

// ---- persistent LSTM scan (128-step chunk), split-fp16 matmul, flag-array barrier ----
// h published as packed hi|lo u32 via device-scope stores (write-through; no dirty L2,
// so no wbl2 on release). Barrier: waitcnt + per-WG flag + parallel 32-lane spin + one
// acquire fence (buffer_inv). xn gate-input loads issued between arrive and wait.
__global__ void __launch_bounds__(256, 1) k_scan4(
    const float* __restrict__ wh, const u16* __restrict__ wlo,
    const float* __restrict__ gh, const float* __restrict__ bh,
    const float* __restrict__ xn, const float* __restrict__ h0l, const float* __restrict__ c0l,
    unsigned* __restrict__ hpubp, float* __restrict__ cspill,
    unsigned long long* __restrict__ istats, unsigned* __restrict__ flags,
    float* __restrict__ ys, float* __restrict__ hn, float* __restrict__ cn,
    int t0, int first) {
  __shared__ u16 pk[32768]; // 64KB: wh_hi fragments [q][kc][lane][8]
  __shared__ float musd[128];
  const int tid = threadIdx.x;
  const int l = tid & 63, w = tid >> 6;
  const int g = blockIdx.x;
  const int lq = l >> 4, ll = l & 15;
  const int hcol = g * 16 + ll;

  for (int c = tid; c < 4096; c += 256) {
    int lane = c & 63, kc = (c >> 6) & 15, q = c >> 10;
    int gcol = g * 16 + (lane & 15) + q * 512;
    int kb = kc * 32 + ((lane >> 4) << 3);
    u16x8 t8;
#pragma unroll
    for (int j = 0; j < 8; ++j)
      t8[j] = __builtin_bit_cast(u16, (f16)wh[(size_t)(kb + j) * 2048 + gcol]);
    *(u16x8*)(pk + (size_t)c * 8) = t8;
  }
  const u16* wloG = wlo + (size_t)g * 32768;
  float gam[4], bet[4];
#pragma unroll
  for (int q = 0; q < 4; ++q) { int gc = hcol + q * 512; gam[q] = gh[gc]; bet[q] = bh[gc]; }
  float cr[4];
#pragma unroll
  for (int j = 0; j < 4; ++j) {
    int r = w * 16 + lq * 4 + j;
    cr[j] = first ? c0l[r * 512 + hcol] : cspill[r * 512 + hcol];
  }
  if (first) {
    for (int u = tid; u < 1024; u += 256) {
      int row = 2 * g + (u >> 9), col = u & 511;
      __hip_atomic_store(&hpubp[row * 512 + col], split2(h0l[row * 512 + col]),
                         __ATOMIC_RELAXED, __HIP_MEMORY_SCOPE_AGENT);
    }
  }
  unsigned bid = 0;
#define BAR_ARRIVE()                                                                         \
  do {                                                                                       \
    bid++;                                                                                   \
    asm volatile("s_waitcnt vmcnt(0)" ::: "memory");                                         \
    __syncthreads();                                                                         \
    if (tid == 0)                                                                            \
      __hip_atomic_store(&flags[g * 32], bid, __ATOMIC_RELAXED, __HIP_MEMORY_SCOPE_AGENT);   \
  } while (0)
#define BAR_WAIT()                                                                           \
  do {                                                                                       \
    if (tid < NWG)                                                                           \
      while (__hip_atomic_load(&flags[tid * 32], __ATOMIC_RELAXED,                           \
                               __HIP_MEMORY_SCOPE_AGENT) < bid) {}                           \
    __builtin_amdgcn_fence(__ATOMIC_ACQUIRE, "agent");                                       \
  } while (0)

  BAR_ARRIVE();
  BAR_WAIT();
  __syncthreads();

  for (int t = 0; t < 128; ++t) {
    const int p = (t0 + t) & 1;
    // ---- phase A: y = h @ W (split fp16), h read as packed u32, unpacked via v_perm ----
    f32x4 acc0[4] = {}, acc1[4] = {};
#pragma unroll
    for (int kc = 0; kc < 16; ++kc) {
      const unsigned* hp = hpubp + ((size_t)(w * 16 + ll) * 512 + kc * 32 + lq * 8);
      uint4 pa = *(const uint4*)hp;
      uint4 pb = *(const uint4*)(hp + 4);
      u32x4 ahw, alw;
      ahw[0] = __builtin_amdgcn_perm(pa.y, pa.x, 0x05040100u);
      ahw[1] = __builtin_amdgcn_perm(pa.w, pa.z, 0x05040100u);
      ahw[2] = __builtin_amdgcn_perm(pb.y, pb.x, 0x05040100u);
      ahw[3] = __builtin_amdgcn_perm(pb.w, pb.z, 0x05040100u);
      alw[0] = __builtin_amdgcn_perm(pa.y, pa.x, 0x07060302u);
      alw[1] = __builtin_amdgcn_perm(pa.w, pa.z, 0x07060302u);
      alw[2] = __builtin_amdgcn_perm(pb.y, pb.x, 0x07060302u);
      alw[3] = __builtin_amdgcn_perm(pb.w, pb.z, 0x07060302u);
      f16x8 ah = __builtin_bit_cast(f16x8, ahw);
      f16x8 al = __builtin_bit_cast(f16x8, alw);
#pragma unroll
      for (int q = 0; q < 4; ++q) {
        f16x8 bhv = *(const f16x8*)(pk + ((size_t)(q * 16 + kc) * 64 + l) * 8);
        f16x8 blv = *(const f16x8*)(wloG + ((size_t)(q * 16 + kc) * 64 + l) * 8);
        acc0[q] = __builtin_amdgcn_mfma_f32_16x16x32_f16(ah, bhv, acc0[q], 0, 0, 0);
        acc1[q] = __builtin_amdgcn_mfma_f32_16x16x32_f16(ah, blv, acc1[q], 0, 0, 0);
        acc1[q] = __builtin_amdgcn_mfma_f32_16x16x32_f16(al, bhv, acc1[q], 0, 0, 0);
      }
    }
    float y[4][4];
#pragma unroll
    for (int q = 0; q < 4; ++q)
#pragma unroll
      for (int j = 0; j < 4; ++j)
        y[q][j] = acc0[q][j] + acc1[q][j] * (1.0f / 2048.0f);

    // per-WG LN stat partials -> fixed-point i64 atomic combine (deterministic)
    float s1[4], s2[4];
#pragma unroll
    for (int j = 0; j < 4; ++j) {
      s1[j] = y[0][j] + y[1][j] + y[2][j] + y[3][j];
      s2[j] = y[0][j] * y[0][j] + y[1][j] * y[1][j] + y[2][j] * y[2][j] + y[3][j] * y[3][j];
    }
#pragma unroll
    for (int m = 1; m <= 8; m <<= 1)
#pragma unroll
      for (int j = 0; j < 4; ++j) {
        s1[j] += __shfl_xor(s1[j], m, 64);
        s2[j] += __shfl_xor(s2[j], m, 64);
      }
    if (ll < 8) {
      int j = ll >> 1;
      int r = w * 16 + lq * 4 + j;
      float v = (ll & 1) ? s2[j] : s1[j];
      long long qv = (long long)((double)v * 4294967296.0);
      atomicAdd(&istats[p * 128 + r * 2 + (ll & 1)], (unsigned long long)qv);
    }
    // ---- barrier 1 (stats); xn loads overlap the wait ----
    BAR_ARRIVE();
    float xp[16];
    {
      const float* xrow = xn + (size_t)t * 64 * 2048;
#pragma unroll
      for (int q = 0; q < 4; ++q)
#pragma unroll
        for (int j = 0; j < 4; ++j)
          xp[q * 4 + j] = xrow[(size_t)(w * 16 + lq * 4 + j) * 2048 + hcol + q * 512];
    }
    BAR_WAIT();
    if (tid < 64) {
      long long a1 = (long long)__hip_atomic_load(&istats[p * 128 + tid * 2], __ATOMIC_RELAXED,
                                                  __HIP_MEMORY_SCOPE_AGENT);
      long long a2 = (long long)__hip_atomic_load(&istats[p * 128 + tid * 2 + 1], __ATOMIC_RELAXED,
                                                  __HIP_MEMORY_SCOPE_AGENT);
      float mu = (float)((double)a1 * (1.0 / (4294967296.0 * 2048.0)));
      float ex2 = (float)((double)a2 * (1.0 / (4294967296.0 * 2048.0)));
      musd[tid] = mu;
      musd[64 + tid] = 1.0f / sqrtf(ex2 - mu * mu + 1e-5f);
    }
    __syncthreads();
    if (tid < 4)
      __hip_atomic_store(&istats[(1 - p) * 128 + g * 4 + tid], 0ull, __ATOMIC_RELAXED,
                         __HIP_MEMORY_SCOPE_AGENT);
    // ---- phase B: LN, gates, state update, publish ----
#pragma unroll
    for (int j = 0; j < 4; ++j) {
      int r = w * 16 + lq * 4 + j;
      float mu = musd[r], rstd = musd[64 + r];
      float gv[4];
#pragma unroll
      for (int q = 0; q < 4; ++q)
        gv[q] = (y[q][j] - mu) * rstd * gam[q] + bet[q] + xp[q * 4 + j];
      float fi = 1.f / (1.f + expf(-gv[0]));
      float ff = 1.f / (1.f + expf(-gv[1]));
      float fo = 1.f / (1.f + expf(-gv[2]));
      float fu = tanhf(gv[3]);
      cr[j] = ff * cr[j] + fi * fu;
      float h = fo * tanhf(cr[j]);
      unsigned s = split2(h);
      size_t ro = (size_t)r * 512 + hcol;
      __hip_atomic_store(&hpubp[ro], s, __ATOMIC_RELAXED, __HIP_MEMORY_SCOPE_AGENT);
      __hip_atomic_store(&ys[(size_t)t * 32768 + ro], h, __ATOMIC_RELAXED, __HIP_MEMORY_SCOPE_AGENT);
      if (t == 127)
        __hip_atomic_store(&cspill[ro], cr[j], __ATOMIC_RELAXED, __HIP_MEMORY_SCOPE_AGENT);
      if (t0 + t == 255) {
        __hip_atomic_store(&hn[ro], h, __ATOMIC_RELAXED, __HIP_MEMORY_SCOPE_AGENT);
        __hip_atomic_store(&cn[ro], cr[j], __ATOMIC_RELAXED, __HIP_MEMORY_SCOPE_AGENT);
      }
    }
    // ---- barrier 2 (h published) ----
    BAR_ARRIVE();
    BAR_WAIT();
    __syncthreads();
  }
#undef BAR_ARRIVE
#undef BAR_WAIT
}

// ---- workspace layout (bytes), max ~76.3 MB (proven-safe region: R5 ran at 80 MB) ----
#define XN_OFF  0ull         // 128*64*2048 fp32 = 64MB (xn chunk)
#define WXH_OFF 67108864ull  // 2*2048*512 f16 = 4MB
#define WXL_OFF 71303168ull  // 4MB
#define WLO_OFF 75497472ull  // 2*131072*8 u16 = 4MB
#define HPP_OFF 79691776ull  // 64*512 u32 = 128KB (packed h hi|lo)
#define CSP_OFF 79822848ull  // 64*512 f32 = 128KB
#define IST_OFF 79953920ull  // 256 u64 = 2KB
#define FLG_OFF 79955968ull  // 4 regions * 2048 u32 = 32KB

extern "C" void kernel_launch(void* const* d_in, const int* in_sizes, int n_in,
                              void* d_out, int out_size, void* d_ws, size_t ws_size,
                              hipStream_t stream) {
  const float* inputs = (const float*)d_in[0];
  const float* h0 = (const float*)d_in[1];
  const float* c0 = (const float*)d_in[2];
  const float* wx = (const float*)d_in[3];
  const float* wh = (const float*)d_in[4];
  const float* bias = (const float*)d_in[5];
  const float* gx = (const float*)d_in[6];
  const float* bxp = (const float*)d_in[7];
  const float* ghp = (const float*)d_in[8];
  const float* bhp = (const float*)d_in[9];
  float* out = (float*)d_out;
  char* ws = (char*)d_ws;

  float* xn = (float*)(ws + XN_OFF);
  u16* wxh = (u16*)(ws + WXH_OFF);
  u16* wxl = (u16*)(ws + WXL_OFF);
  u16* wlo = (u16*)(ws + WLO_OFF);
  unsigned* hpp = (unsigned*)(ws + HPP_OFF);
  float* csp = (float*)(ws + CSP_OFF);
  unsigned long long* ist = (unsigned long long*)(ws + IST_OFF);
  unsigned* flg = (unsigned*)(ws + FLG_OFF);

  k_zero<<<32, 256, 0, stream>>>(ist, flg);
  k_wsplit<<<dim3(64, 16, 2), dim3(32, 8), 0, stream>>>(wx, wxh, wxl);
  k_wlo<<<1024, 256, 0, stream>>>(wh, wlo);

  for (int l = 0; l < 2; ++l) {
    const float* Abase = (l == 0) ? inputs : out; // layer-1 input = layer-0 ys (fp32 in d_out.x)
    for (int k = 0; k < 2; ++k) {
      k_gemm3<<<dim3(16, 64), 256, 0, stream>>>(Abase + (size_t)k * 8192 * 512,
                                                wxh + (size_t)l * 2048 * 512,
                                                wxl + (size_t)l * 2048 * 512, xn, 2048, 512);
      k_ln2<<<8192, 256, 0, stream>>>(xn, gx + l * 2048, bxp + l * 2048, bias + l * 2048);
      k_scan4<<<NWG, 256, 0, stream>>>(wh + (size_t)l * 1048576, wlo + (size_t)l * 1048576,
                                       ghp + l * 2048, bhp + l * 2048, xn,
                                       h0 + (size_t)l * 32768, c0 + (size_t)l * 32768,
                                       hpp, csp, ist, flg + (size_t)(l * 2 + k) * 2048,
                                       out + (size_t)k * 128 * 32768,
                                       out + 8388608 + (size_t)l * 32768,
                                       out + 8388608 + 65536 + (size_t)l * 32768,
                                       k * 128, (k == 0) ? 1 : 0);
    }
  }
}